// Round 13
// baseline (173.048 us; speedup 1.0000x reference)
//
#include <hip/hip_runtime.h>
#include <stdint.h>

// ============================================================================
// Fused attention block: out = proj( MHA_causal( x @ w_attn + b_attn ) )
// B=4, S=2048, E=1024, H=16, D=64.  bf16 MFMA path, f32 accumulation.
//
// Pipeline:
//   1) cast_x_kernel:        x f32 -> xb bf16                  [8192][1024]
//   2) transpose_cast:       w_attn -> wat bf16 [3072][1024] (B^T form)
//                            w_proj -> wpt bf16 [1024][1024]
//   3) gemm256<bf16,FUSE_VT>: qkv(Q,K) + vt(V) = xb @ wat^T + b [8192][3072]
//        v4 schedule (BK=32, triple-buffer, counted vmcnt(3), 1 barrier/tile)
//        + FUSED V-transpose: cols>=2048 written straight into
//        vt[bh][d][key-permuted s] (inverse of flash's in-lane-pack permute);
//        V is NOT written to qkv. vtrans kernel deleted.
//        Q columns (<1024) pre-scaled by log2e/8 for exp2-domain softmax.
//   4) flash_kernel v10:     ob = causal attention             [8192][1024]
//        4 waves x 2 q-sets (fragment sharing) x UNPAIRED grid (16,64) =
//        1024 blocks -> 4 blocks/CU co-resident (16 waves/CU), heavy-first.
//        v9's pairing capped co-residency at 8 waves/CU; round-9's clamp
//        issue avoided via (256,4) (VGPR 64).
//   5) gemm256<float>:       out = ob @ wpt^T + b_proj         [8192][1024]
// ============================================================================

typedef __bf16 bf16;
typedef __bf16 bf16x4 __attribute__((ext_vector_type(4)));
typedef __bf16 bf16x8 __attribute__((ext_vector_type(8)));
typedef float  f32x4  __attribute__((ext_vector_type(4)));

#define DEV __device__ __forceinline__

// async global->LDS, 16B per lane. LDS dest: wave-uniform base; HW adds lane*16.
DEV void async_copy16(bf16* lds, const bf16* g) {
  __builtin_amdgcn_global_load_lds(
      (__attribute__((address_space(1))) void*)(uintptr_t)g,
      (__attribute__((address_space(3))) void*)(uint32_t)(uintptr_t)lds,
      16, 0, 0);
}

// ---------------------------------------------------------------------------
// prep kernels
// ---------------------------------------------------------------------------
__global__ __launch_bounds__(256) void cast_x_kernel(const float* __restrict__ in,
                                                     bf16* __restrict__ out, int n4) {
  int i = blockIdx.x * blockDim.x + threadIdx.x;
  int stride = gridDim.x * blockDim.x;
  for (; i < n4; i += stride) {
    float4 v = ((const float4*)in)[i];
    bf16x4 o = { (bf16)v.x, (bf16)v.y, (bf16)v.z, (bf16)v.w };
    *(bf16x4*)(out + (size_t)i * 4) = o;
  }
}

// W [Kd][Nd] f32 row-major  ->  Wt [Nd][Kd] bf16 row-major
__global__ __launch_bounds__(256) void transpose_cast_kernel(const float* __restrict__ W,
                                                             bf16* __restrict__ Wt,
                                                             int Kd, int Nd) {
  __shared__ alignas(16) bf16 T[64 * 80];   // 64x64 tile, padded rows
  const int t = threadIdx.x;
  const int n0 = blockIdx.x * 64;
  const int k0 = blockIdx.y * 64;
#pragma unroll
  for (int i = 0; i < 4; ++i) {
    int idx = t + i * 256;            // 1024 float4s
    int r  = idx >> 4;                // k row in tile
    int c4 = (idx & 15) * 4;          // n col in tile
    float4 v = *(const float4*)(W + (size_t)(k0 + r) * Nd + n0 + c4);
    bf16x4 o = { (bf16)v.x, (bf16)v.y, (bf16)v.z, (bf16)v.w };
    *(bf16x4*)(&T[r * 80 + c4]) = o;
  }
  __syncthreads();
#pragma unroll
  for (int i = 0; i < 2; ++i) {
    int idx = t + i * 256;            // 512 out-chunks
    int n = idx >> 3;
    int c = idx & 7;
    bf16x8 o;
#pragma unroll
    for (int j = 0; j < 8; ++j) o[j] = T[(c * 8 + j) * 80 + n];
    *(bf16x8*)(Wt + (size_t)(n0 + n) * Kd + k0 + c * 8) = o;
  }
}

// ---------------------------------------------------------------------------
// GEMM v5: C[M][N] = A[M][K] @ Bt[N][K]^T + bias[N]
// BM=256, BN=128, BK=32. 512 thr = 8 waves (4M x 2N), 64x64 per wave.
// Triple-buffered LDS (72 KB, 2 blocks/CU), one barrier/K-tile, counted
// vmcnt(3), slot^=(row>>1)&3 swizzle, XCD-bijective block swizzle.
// FUSE_VT: cols in [2048,3072) are written to vtout[bh][d][perm(s)] instead
// of C (inverse of the flash in-lane-pack key permutation); others to C.
// ---------------------------------------------------------------------------
template <typename OutT, bool FUSE_VT>
__global__ __launch_bounds__(512, 4) void gemm256_kernel(const bf16* __restrict__ A,
                                                         const bf16* __restrict__ Bt,
                                                         const float* __restrict__ bias,
                                                         OutT* __restrict__ C,
                                                         bf16* __restrict__ vtout,
                                                         int M, int N, int K,
                                                         float qscale, int qcols,
                                                         int nbx) {
  __shared__ alignas(16) bf16 As[3][256 * 32];   // 48 KB
  __shared__ alignas(16) bf16 Bs[3][128 * 32];   // 24 KB

  const int tid  = threadIdx.x;
  const int lane = tid & 63;
  const int w    = tid >> 6;
  const int wm = w >> 1, wn = w & 1;
  const int l15 = lane & 15, l16 = lane >> 4;

  const int nwg = (int)gridDim.x;
  const int cpx = nwg >> 3;
  const int swz = ((int)blockIdx.x & 7) * cpx + ((int)blockIdx.x >> 3);
  const int m0 = (swz / nbx) * 256;
  const int n0 = (swz % nbx) * 128;

  const int c0  = w * 64 + lane;                 // chunk for A j=0 and B
  const int rA0 = c0 >> 2, sA0 = c0 & 3;
  const int rA1 = rA0 + 128;                     // A j=1 (c0+512)
  const bf16* srcA0 = A  + (size_t)(m0 + rA0) * K + 8 * (sA0 ^ ((rA0 >> 1) & 3));
  const bf16* srcA1 = A  + (size_t)(m0 + rA1) * K + 8 * (sA0 ^ ((rA1 >> 1) & 3));
  const bf16* srcB  = Bt + (size_t)(n0 + rA0) * K + 8 * (sA0 ^ ((rA0 >> 1) & 3));

#define STAGE_TILE(buf, kt)                                       \
  {                                                               \
    const int k0_ = (kt) * 32;                                    \
    async_copy16(&As[buf][(w * 64) * 8],         srcA0 + k0_);    \
    async_copy16(&As[buf][(512 + w * 64) * 8],   srcA1 + k0_);    \
    async_copy16(&Bs[buf][(w * 64) * 8],         srcB  + k0_);    \
  }

  f32x4 acc[4][4];
  f32x4 zf = {0.f, 0.f, 0.f, 0.f};
#pragma unroll
  for (int i = 0; i < 4; ++i)
#pragma unroll
    for (int j = 0; j < 4; ++j) acc[i][j] = zf;

  const int KT = K >> 5;
  STAGE_TILE(0, 0)
  STAGE_TILE(1, 1)

  const int soff = 8 * (l16 ^ ((l15 >> 1) & 3));

  int bufc = 0;
  int bufs = 2;
  for (int kt = 0; kt < KT; ++kt) {
    if (kt < KT - 1) { asm volatile("s_waitcnt vmcnt(3)" ::: "memory"); }
    else             { asm volatile("s_waitcnt vmcnt(0)" ::: "memory"); }
    __builtin_amdgcn_s_barrier();
    asm volatile("" ::: "memory");
    if (kt + 2 < KT) STAGE_TILE(bufs, kt + 2)

    bf16x8 bfr[4], afr[4];
#pragma unroll
    for (int n = 0; n < 4; ++n) {
      int rb = wn * 64 + n * 16 + l15;
      bfr[n] = *(const bf16x8*)(&Bs[bufc][rb * 32 + soff]);
    }
#pragma unroll
    for (int m = 0; m < 4; ++m) {
      int ra = wm * 64 + m * 16 + l15;
      afr[m] = *(const bf16x8*)(&As[bufc][ra * 32 + soff]);
    }
    __builtin_amdgcn_s_setprio(1);
#pragma unroll
    for (int m = 0; m < 4; ++m)
#pragma unroll
      for (int n = 0; n < 4; ++n)
        acc[m][n] = __builtin_amdgcn_mfma_f32_16x16x32_bf16(afr[m], bfr[n], acc[m][n], 0, 0, 0);
    __builtin_amdgcn_s_setprio(0);
    asm volatile("" ::: "memory");
    bufc = (bufc == 2) ? 0 : bufc + 1;
    bufs = (bufs == 2) ? 0 : bufs + 1;
  }

  // ---- epilogue
#pragma unroll
  for (int n = 0; n < 4; ++n) {
    int col = n0 + wn * 64 + n * 16 + l15;
    float bb = bias[col];
    if (FUSE_VT && col >= 2048) {
      // V column: write to vt[bh][d][perm(s)] (inverse of flash key permute)
      int hh = (col - 2048) >> 6, d = (col - 2048) & 63;
#pragma unroll
      for (int m = 0; m < 4; ++m) {
#pragma unroll
        for (int reg = 0; reg < 4; ++reg) {
          int row = m0 + wm * 64 + m * 16 + l16 * 4 + reg;
          int s = row & 2047;
          int key = s & 63;
          int pos = (key & 32) | (((key >> 2) & 3) << 3) | (((key >> 4) & 1) << 2) | (key & 3);
          size_t vtaddr = ((size_t)((row >> 11) * 16 + hh) * 64 + d) * 2048 + (s & ~63) + pos;
          vtout[vtaddr] = (bf16)(acc[m][n][reg] + bb);
        }
      }
    } else {
      float sc2 = (col < qcols) ? qscale : 1.0f;
#pragma unroll
      for (int m = 0; m < 4; ++m) {
#pragma unroll
        for (int reg = 0; reg < 4; ++reg) {
          int row = m0 + wm * 64 + m * 16 + l16 * 4 + reg;
          C[(size_t)row * N + col] = (OutT)((acc[m][n][reg] + bb) * sc2);
        }
      }
    }
  }
#undef STAGE_TILE
}

// ---------------------------------------------------------------------------
// Flash attention v10 (causal). Q-tile 128 rows = 4 waves x 2 q-sets of 16.
// UNPAIRED grid (16,64) = 1024 blocks -> 4 blocks/CU co-resident (16 waves/
// CU); heavy tiles first (t = 15-bx) for LPT balance. Fragment sharing: each
// K/V LDS read feeds both q-sets.
// NO-MAX exp2 softmax (Q pre-scaled by log2e/8; masked entries exp2(-1e30)=0).
// P never touches LDS (vt key axis pre-permuted at QKV-GEMM epilogue).
// S^T = mfma(K,Q): lane holds col q = lane&15, 16 keys = kf*16 + l16*4 + reg.
// O^T = mfma(V^T,P^T): lane holds col q = lane&15, d = nf*16 + l16*4 + reg.
// LDS = 32 KB. launch_bounds(256,4): VGPR cap 128 (measured 64 -- no clamp).
// ---------------------------------------------------------------------------
__global__ __launch_bounds__(256, 4) void flash_kernel(const bf16* __restrict__ qkv,
                                                       const bf16* __restrict__ vt,
                                                       bf16* __restrict__ obuf) {
  constexpr int S = 2048, E3 = 3072;
  __shared__ alignas(16) bf16 Ks[2][64 * 64];
  __shared__ alignas(16) bf16 Vs[2][64 * 64];   // V^T tile (key-permuted cols)

  const int tid  = threadIdx.x;
  const int lane = tid & 63;
  const int w    = tid >> 6;       // 0..3
  const int t  = 15 - (int)blockIdx.x;   // heavy tiles dispatched first
  const int bh = blockIdx.y;
  const int b = bh >> 4, h = bh & 15;
  const int l15 = lane & 15, l16 = lane >> 4;

  // staging geometry: wave w stages 1KB chunks 2w, 2w+1 of each 64x64 tile.
  const int sr  = lane >> 3;             // 0..7 (row & 7 -> swizzle xor)
  const int scc = lane & 7;              // 16B slot
  const int r0 = w * 16 + sr;            // rows for chunk 2w
  const int r1 = w * 16 + 8 + sr;        // rows for chunk 2w+1
  const bf16* kst0 = qkv + (size_t)(b * S + r0) * E3 + 1024 + h * 64 + 8 * (scc ^ sr);
  const bf16* kst1 = qkv + (size_t)(b * S + r1) * E3 + 1024 + h * 64 + 8 * (scc ^ sr);
  const bf16* vst0 = vt + (size_t)(bh * 64 + r0) * S + 8 * (scc ^ sr);
  const bf16* vst1 = vt + (size_t)(bh * 64 + r1) * S + 8 * (scc ^ sr);

  // hoisted LDS byte offsets (row stride 128B; XOR term reduces to l15&7)
  const int xsw = l15 & 7;
  const uint32_t rdA = (uint32_t)(l15 * 128 + 16 * (l16 ^ xsw));        // chunk 0
  const uint32_t rdB = (uint32_t)(l15 * 128 + 16 * ((4 + l16) ^ xsw));  // chunk 1

#define KV_STAGE(buf, kv0_)                                          \
  {                                                                  \
    async_copy16(Ks[buf] + (w * 2) * 512,     kst0 + (size_t)(kv0_) * E3); \
    async_copy16(Ks[buf] + (w * 2 + 1) * 512, kst1 + (size_t)(kv0_) * E3); \
    async_copy16(Vs[buf] + (w * 2) * 512,     vst0 + (kv0_));        \
    async_copy16(Vs[buf] + (w * 2 + 1) * 512, vst1 + (kv0_));        \
  }

  const int q0 = t * 128;
  const int wq0 = q0 + w * 32;         // first q row owned by this wave
  const int nsteps = 2 * t + 2;        // even

  KV_STAGE(0, 0)

  // Q fragments global->reg, 2 sets (B-operand: col q = l15)
  bf16x8 qf[2][2];
  {
    const bf16* qbase = qkv + (size_t)(b * S + wq0) * E3 + h * 64;
#pragma unroll
    for (int s = 0; s < 2; ++s)
#pragma unroll
      for (int dk = 0; dk < 2; ++dk)
        qf[s][dk] = *(const bf16x8*)(qbase + (size_t)(s * 16 + l15) * E3 + (dk * 4 + l16) * 8);
  }

  float lstate[2] = {0.f, 0.f};
  f32x4 oacc[2][4];
  f32x4 zf = {0.f, 0.f, 0.f, 0.f};
#pragma unroll
  for (int s = 0; s < 2; ++s)
#pragma unroll
    for (int i = 0; i < 4; ++i) oacc[s][i] = zf;

  __syncthreads();   // step-0 K/V staged (vmcnt drained by barrier)

#define FLASH_STEP(CUR, STEPIDX)                                                  \
    {                                                                             \
      const int kv0 = (STEPIDX) * 64;                                             \
      if ((STEPIDX) + 1 < nsteps) KV_STAGE((CUR) ^ 1, kv0 + 64)                   \
      if (kv0 <= wq0 + 31) {   /* wave-uniform dead-step skip */                  \
        f32x4 sv[2][4];                                                           \
        _Pragma("unroll")                                                         \
        for (int kf = 0; kf < 4; ++kf) { sv[0][kf] = zf; sv[1][kf] = zf; }        \
        __builtin_amdgcn_s_setprio(1);                                            \
        _Pragma("unroll")                                                         \
        for (int kf = 0; kf < 4; ++kf) {                                          \
          bf16x8 k0 = *(const bf16x8*)((const char*)Ks[CUR] + rdA + kf * 2048);   \
          sv[0][kf] = __builtin_amdgcn_mfma_f32_16x16x32_bf16(k0, qf[0][0], sv[0][kf], 0, 0, 0); \
          sv[1][kf] = __builtin_amdgcn_mfma_f32_16x16x32_bf16(k0, qf[1][0], sv[1][kf], 0, 0, 0); \
          bf16x8 k1 = *(const bf16x8*)((const char*)Ks[CUR] + rdB + kf * 2048);   \
          sv[0][kf] = __builtin_amdgcn_mfma_f32_16x16x32_bf16(k1, qf[0][1], sv[0][kf], 0, 0, 0); \
          sv[1][kf] = __builtin_amdgcn_mfma_f32_16x16x32_bf16(k1, qf[1][1], sv[1][kf], 0, 0, 0); \
        }                                                                         \
        __builtin_amdgcn_s_setprio(0);                                            \
        bf16x8 pb[2][2];                                                          \
        _Pragma("unroll")                                                         \
        for (int s = 0; s < 2; ++s) {                                             \
          if (kv0 + 63 > wq0 + s * 16) {   /* causal mask, per set */             \
            const int qrow_ = wq0 + s * 16 + l15;                                 \
            _Pragma("unroll")                                                     \
            for (int kf = 0; kf < 4; ++kf)                                        \
              _Pragma("unroll")                                                   \
              for (int reg = 0; reg < 4; ++reg) {                                 \
                int key = kv0 + kf * 16 + l16 * 4 + reg;                          \
                if (key > qrow_) sv[s][kf][reg] = -1e30f;                         \
              }                                                                   \
          }                                                                       \
          float rsum = 0.f;                                                       \
          _Pragma("unroll")                                                       \
          for (int kf = 0; kf < 4; ++kf)                                          \
            _Pragma("unroll")                                                     \
            for (int reg = 0; reg < 4; ++reg) {                                   \
              float p = __builtin_amdgcn_exp2f(sv[s][kf][reg]);                   \
              sv[s][kf][reg] = p;                                                 \
              rsum += p;                                                          \
            }                                                                     \
          rsum += __shfl_xor(rsum, 16);                                           \
          rsum += __shfl_xor(rsum, 32);                                           \
          lstate[s] += rsum;                                                      \
          _Pragma("unroll")                                                       \
          for (int kc = 0; kc < 2; ++kc) {                                        \
            bf16x8 tq;                                                            \
            tq[0] = (bf16)sv[s][2 * kc][0];  tq[1] = (bf16)sv[s][2 * kc][1];      \
            tq[2] = (bf16)sv[s][2 * kc][2];  tq[3] = (bf16)sv[s][2 * kc][3];      \
            tq[4] = (bf16)sv[s][2 * kc + 1][0]; tq[5] = (bf16)sv[s][2 * kc + 1][1]; \
            tq[6] = (bf16)sv[s][2 * kc + 1][2]; tq[7] = (bf16)sv[s][2 * kc + 1][3]; \
            pb[s][kc] = tq;                                                       \
          }                                                                       \
        }                                                                         \
        __builtin_amdgcn_s_setprio(1);                                            \
        _Pragma("unroll")                                                         \
        for (int nf = 0; nf < 4; ++nf) {                                          \
          bf16x8 vf0 = *(const bf16x8*)((const char*)Vs[CUR] + rdA + nf * 2048);  \
          oacc[0][nf] = __builtin_amdgcn_mfma_f32_16x16x32_bf16(vf0, pb[0][0], oacc[0][nf], 0, 0, 0); \
          oacc[1][nf] = __builtin_amdgcn_mfma_f32_16x16x32_bf16(vf0, pb[1][0], oacc[1][nf], 0, 0, 0); \
          bf16x8 vf1 = *(const bf16x8*)((const char*)Vs[CUR] + rdB + nf * 2048);  \
          oacc[0][nf] = __builtin_amdgcn_mfma_f32_16x16x32_bf16(vf1, pb[0][1], oacc[0][nf], 0, 0, 0); \
          oacc[1][nf] = __builtin_amdgcn_mfma_f32_16x16x32_bf16(vf1, pb[1][1], oacc[1][nf], 0, 0, 0); \
        }                                                                         \
        __builtin_amdgcn_s_setprio(0);                                            \
      }                                                                           \
      __syncthreads();   /* next buffer staged + all waves done with CUR */       \
    }

  for (int step = 0; step < nsteps; step += 2) {
    FLASH_STEP(0, step)
    FLASH_STEP(1, step + 1)
  }
#undef FLASH_STEP

  // ---- normalize and store: lane owns q row per set; d = nf*16 + l16*4 + reg
#pragma unroll
  for (int s = 0; s < 2; ++s) {
    float inv = 1.0f / lstate[s];
    int qrow = wq0 + s * 16 + l15;
#pragma unroll
    for (int nf = 0; nf < 4; ++nf) {
      bf16x4 o4 = { (bf16)(oacc[s][nf][0] * inv), (bf16)(oacc[s][nf][1] * inv),
                    (bf16)(oacc[s][nf][2] * inv), (bf16)(oacc[s][nf][3] * inv) };
      *(bf16x4*)(obuf + (size_t)(b * S + qrow) * 1024 + h * 64 + nf * 16 + l16 * 4) = o4;
    }
  }
#undef KV_STAGE
}

// ---------------------------------------------------------------------------
extern "C" void kernel_launch(void* const* d_in, const int* in_sizes, int n_in,
                              void* d_out, int out_size, void* d_ws, size_t ws_size,
                              hipStream_t stream) {
  (void)in_sizes; (void)n_in; (void)out_size; (void)ws_size;
  const float* x      = (const float*)d_in[0];
  const float* w_attn = (const float*)d_in[1];
  const float* b_attn = (const float*)d_in[2];
  const float* w_proj = (const float*)d_in[3];
  const float* b_proj = (const float*)d_in[4];
  float* out = (float*)d_out;

  char* ws = (char*)d_ws;
  bf16* xb  = (bf16*)(ws + 0);          // 8192*1024*2  = 16777216
  bf16* wat = (bf16*)(ws + 16777216);   // 3072*1024*2  =  6291456
  bf16* wpt = (bf16*)(ws + 23068672);   // 1024*1024*2  =  2097152
  bf16* qkv = (bf16*)(ws + 25165824);   // 8192*3072*2  = 50331648
  bf16* vt  = (bf16*)(ws + 75497472);   // 64*64*2048*2 = 16777216
  bf16* ob  = (bf16*)(ws + 92274688);   // 8192*1024*2  = 16777216 (end 109051904)

  const float QSCALE = 0.18033688011112042f;   // log2(e) / sqrt(64)

  cast_x_kernel<<<2048, 256, 0, stream>>>(x, xb, 8192 * 1024 / 4);
  transpose_cast_kernel<<<dim3(48, 16), 256, 0, stream>>>(w_attn, wat, 1024, 3072);
  transpose_cast_kernel<<<dim3(16, 16), 256, 0, stream>>>(w_proj, wpt, 1024, 1024);
  // QKV (+fused V-transpose): grid (8192/256)*(3072/128) = 768 blocks (%8==0)
  gemm256_kernel<bf16, true><<<768, 512, 0, stream>>>(xb, wat, b_attn, qkv, vt,
                                                      8192, 3072, 1024, QSCALE, 1024, 24);
  flash_kernel<<<dim3(16, 64), 256, 0, stream>>>(qkv, vt, ob);
  // proj: grid (8192/256)*(1024/128) = 256 blocks (%8==0)
  gemm256_kernel<float, false><<<256, 512, 0, stream>>>(ob, wpt, b_proj, out, nullptr,
                                                        8192, 1024, 1024, 1.0f, 0, 8);
}

// Round 14
// 159.201 us; speedup vs baseline: 1.0870x; 1.0870x over previous
//
#include <hip/hip_runtime.h>
#include <stdint.h>

// ============================================================================
// Fused attention block: out = proj( MHA_causal( x @ w_attn + b_attn ) )
// B=4, S=2048, E=1024, H=16, D=64.  bf16 MFMA path, f32 accumulation.
//
// Pipeline:
//   1) cast_x_kernel:        x f32 -> xb bf16                  [8192][1024]
//   2) transpose_cast:       w_attn -> wat bf16 [3072][1024] (B^T form)
//                            w_proj -> wpt bf16 [1024][1024]
//   3) gemm256<bf16,FUSE_VT>: qkv(Q,K) + vt(V) = xb @ wat^T + b [8192][3072]
//        v4 schedule (BK=32, triple-buffer, counted vmcnt(3), 1 barrier/tile)
//        + fused V-transpose into vt (key-permuted; V not written to qkv).
//        Q columns (<1024) pre-scaled by log2e/8 for exp2-domain softmax.
//   4) flash_kernel v11:     ob = causal attention             [8192][1024]
//        PAIRED blocks (bx,15-bx) -> exactly 36 steps/block (v10's unpaired
//        grid == capacity -> static imbalance, regressed). 4 waves x 2 q-sets
//        (fragment sharing). NEW: K/V TRIPLE-buffer + ONE raw s_barrier/step
//        + counted s_waitcnt vmcnt(4) (vmcnt(0) only on final step) -- the
//        __syncthreads-per-step vmcnt(0) drain was ~60% of step time.
//   5) gemm256<float>:       out = ob @ wpt^T + b_proj         [8192][1024]
// ============================================================================

typedef __bf16 bf16;
typedef __bf16 bf16x4 __attribute__((ext_vector_type(4)));
typedef __bf16 bf16x8 __attribute__((ext_vector_type(8)));
typedef float  f32x4  __attribute__((ext_vector_type(4)));

#define DEV __device__ __forceinline__

// async global->LDS, 16B per lane. LDS dest: wave-uniform base; HW adds lane*16.
DEV void async_copy16(bf16* lds, const bf16* g) {
  __builtin_amdgcn_global_load_lds(
      (__attribute__((address_space(1))) void*)(uintptr_t)g,
      (__attribute__((address_space(3))) void*)(uint32_t)(uintptr_t)lds,
      16, 0, 0);
}

// ---------------------------------------------------------------------------
// prep kernels
// ---------------------------------------------------------------------------
__global__ __launch_bounds__(256) void cast_x_kernel(const float* __restrict__ in,
                                                     bf16* __restrict__ out, int n4) {
  int i = blockIdx.x * blockDim.x + threadIdx.x;
  int stride = gridDim.x * blockDim.x;
  for (; i < n4; i += stride) {
    float4 v = ((const float4*)in)[i];
    bf16x4 o = { (bf16)v.x, (bf16)v.y, (bf16)v.z, (bf16)v.w };
    *(bf16x4*)(out + (size_t)i * 4) = o;
  }
}

// W [Kd][Nd] f32 row-major  ->  Wt [Nd][Kd] bf16 row-major
__global__ __launch_bounds__(256) void transpose_cast_kernel(const float* __restrict__ W,
                                                             bf16* __restrict__ Wt,
                                                             int Kd, int Nd) {
  __shared__ alignas(16) bf16 T[64 * 80];   // 64x64 tile, padded rows
  const int t = threadIdx.x;
  const int n0 = blockIdx.x * 64;
  const int k0 = blockIdx.y * 64;
#pragma unroll
  for (int i = 0; i < 4; ++i) {
    int idx = t + i * 256;            // 1024 float4s
    int r  = idx >> 4;                // k row in tile
    int c4 = (idx & 15) * 4;          // n col in tile
    float4 v = *(const float4*)(W + (size_t)(k0 + r) * Nd + n0 + c4);
    bf16x4 o = { (bf16)v.x, (bf16)v.y, (bf16)v.z, (bf16)v.w };
    *(bf16x4*)(&T[r * 80 + c4]) = o;
  }
  __syncthreads();
#pragma unroll
  for (int i = 0; i < 2; ++i) {
    int idx = t + i * 256;            // 512 out-chunks
    int n = idx >> 3;
    int c = idx & 7;
    bf16x8 o;
#pragma unroll
    for (int j = 0; j < 8; ++j) o[j] = T[(c * 8 + j) * 80 + n];
    *(bf16x8*)(Wt + (size_t)(n0 + n) * Kd + k0 + c * 8) = o;
  }
}

// ---------------------------------------------------------------------------
// GEMM v5: C[M][N] = A[M][K] @ Bt[N][K]^T + bias[N]
// BM=256, BN=128, BK=32. 512 thr = 8 waves (4M x 2N), 64x64 per wave.
// Triple-buffered LDS (72 KB, 2 blocks/CU), one barrier/K-tile, counted
// vmcnt(3), slot^=(row>>1)&3 swizzle, XCD-bijective block swizzle.
// FUSE_VT: cols in [2048,3072) are written to vtout[bh][d][perm(s)] instead
// of C (inverse of the flash in-lane-pack key permutation); others to C.
// ---------------------------------------------------------------------------
template <typename OutT, bool FUSE_VT>
__global__ __launch_bounds__(512, 4) void gemm256_kernel(const bf16* __restrict__ A,
                                                         const bf16* __restrict__ Bt,
                                                         const float* __restrict__ bias,
                                                         OutT* __restrict__ C,
                                                         bf16* __restrict__ vtout,
                                                         int M, int N, int K,
                                                         float qscale, int qcols,
                                                         int nbx) {
  __shared__ alignas(16) bf16 As[3][256 * 32];   // 48 KB
  __shared__ alignas(16) bf16 Bs[3][128 * 32];   // 24 KB

  const int tid  = threadIdx.x;
  const int lane = tid & 63;
  const int w    = tid >> 6;
  const int wm = w >> 1, wn = w & 1;
  const int l15 = lane & 15, l16 = lane >> 4;

  const int nwg = (int)gridDim.x;
  const int cpx = nwg >> 3;
  const int swz = ((int)blockIdx.x & 7) * cpx + ((int)blockIdx.x >> 3);
  const int m0 = (swz / nbx) * 256;
  const int n0 = (swz % nbx) * 128;

  const int c0  = w * 64 + lane;                 // chunk for A j=0 and B
  const int rA0 = c0 >> 2, sA0 = c0 & 3;
  const int rA1 = rA0 + 128;                     // A j=1 (c0+512)
  const bf16* srcA0 = A  + (size_t)(m0 + rA0) * K + 8 * (sA0 ^ ((rA0 >> 1) & 3));
  const bf16* srcA1 = A  + (size_t)(m0 + rA1) * K + 8 * (sA0 ^ ((rA1 >> 1) & 3));
  const bf16* srcB  = Bt + (size_t)(n0 + rA0) * K + 8 * (sA0 ^ ((rA0 >> 1) & 3));

#define STAGE_TILE(buf, kt)                                       \
  {                                                               \
    const int k0_ = (kt) * 32;                                    \
    async_copy16(&As[buf][(w * 64) * 8],         srcA0 + k0_);    \
    async_copy16(&As[buf][(512 + w * 64) * 8],   srcA1 + k0_);    \
    async_copy16(&Bs[buf][(w * 64) * 8],         srcB  + k0_);    \
  }

  f32x4 acc[4][4];
  f32x4 zf = {0.f, 0.f, 0.f, 0.f};
#pragma unroll
  for (int i = 0; i < 4; ++i)
#pragma unroll
    for (int j = 0; j < 4; ++j) acc[i][j] = zf;

  const int KT = K >> 5;
  STAGE_TILE(0, 0)
  STAGE_TILE(1, 1)

  const int soff = 8 * (l16 ^ ((l15 >> 1) & 3));

  int bufc = 0;
  int bufs = 2;
  for (int kt = 0; kt < KT; ++kt) {
    if (kt < KT - 1) { asm volatile("s_waitcnt vmcnt(3)" ::: "memory"); }
    else             { asm volatile("s_waitcnt vmcnt(0)" ::: "memory"); }
    __builtin_amdgcn_s_barrier();
    asm volatile("" ::: "memory");
    if (kt + 2 < KT) STAGE_TILE(bufs, kt + 2)

    bf16x8 bfr[4], afr[4];
#pragma unroll
    for (int n = 0; n < 4; ++n) {
      int rb = wn * 64 + n * 16 + l15;
      bfr[n] = *(const bf16x8*)(&Bs[bufc][rb * 32 + soff]);
    }
#pragma unroll
    for (int m = 0; m < 4; ++m) {
      int ra = wm * 64 + m * 16 + l15;
      afr[m] = *(const bf16x8*)(&As[bufc][ra * 32 + soff]);
    }
    __builtin_amdgcn_s_setprio(1);
#pragma unroll
    for (int m = 0; m < 4; ++m)
#pragma unroll
      for (int n = 0; n < 4; ++n)
        acc[m][n] = __builtin_amdgcn_mfma_f32_16x16x32_bf16(afr[m], bfr[n], acc[m][n], 0, 0, 0);
    __builtin_amdgcn_s_setprio(0);
    asm volatile("" ::: "memory");
    bufc = (bufc == 2) ? 0 : bufc + 1;
    bufs = (bufs == 2) ? 0 : bufs + 1;
  }

  // ---- epilogue
#pragma unroll
  for (int n = 0; n < 4; ++n) {
    int col = n0 + wn * 64 + n * 16 + l15;
    float bb = bias[col];
    if (FUSE_VT && col >= 2048) {
      // V column: write to vt[bh][d][perm(s)] (inverse of flash key permute)
      int hh = (col - 2048) >> 6, d = (col - 2048) & 63;
#pragma unroll
      for (int m = 0; m < 4; ++m) {
#pragma unroll
        for (int reg = 0; reg < 4; ++reg) {
          int row = m0 + wm * 64 + m * 16 + l16 * 4 + reg;
          int s = row & 2047;
          int key = s & 63;
          int pos = (key & 32) | (((key >> 2) & 3) << 3) | (((key >> 4) & 1) << 2) | (key & 3);
          size_t vtaddr = ((size_t)((row >> 11) * 16 + hh) * 64 + d) * 2048 + (s & ~63) + pos;
          vtout[vtaddr] = (bf16)(acc[m][n][reg] + bb);
        }
      }
    } else {
      float sc2 = (col < qcols) ? qscale : 1.0f;
#pragma unroll
      for (int m = 0; m < 4; ++m) {
#pragma unroll
        for (int reg = 0; reg < 4; ++reg) {
          int row = m0 + wm * 64 + m * 16 + l16 * 4 + reg;
          C[(size_t)row * N + col] = (OutT)((acc[m][n][reg] + bb) * sc2);
        }
      }
    }
  }
#undef STAGE_TILE
}

// ---------------------------------------------------------------------------
// Flash attention v11 (causal). Q-tile 128 rows = 4 waves x 2 q-sets of 16.
// Paired blocks (bx, 15-bx) -> exactly 36 KV-steps/block; grid (8,64) = 512.
// TRIPLE-buffered K/V (48 KB), ONE raw s_barrier per step with counted
// s_waitcnt vmcnt(4) (vmcnt(0) only on the final step) -- prefetch loads for
// tiles kt+1, kt+2 stay in flight across barriers (T4). Pre-loop
// __syncthreads establishes the drain invariant; buffer (kt+2)%3's previous
// readers (iteration kt-1) are fenced by this step's top barrier.
// Fragment sharing: each K/V LDS read feeds both q-sets.
// NO-MAX exp2 softmax (Q pre-scaled by log2e/8; masked entries exp2(-1e30)=0).
// P never touches LDS (vt key axis pre-permuted at QKV-GEMM epilogue).
// S^T = mfma(K,Q): lane holds col q = lane&15, 16 keys = kf*16 + l16*4 + reg.
// O^T = mfma(V^T,P^T): lane holds col q = lane&15, d = nf*16 + l16*4 + reg.
// ---------------------------------------------------------------------------
__global__ __launch_bounds__(256, 4) void flash_kernel(const bf16* __restrict__ qkv,
                                                       const bf16* __restrict__ vt,
                                                       bf16* __restrict__ obuf) {
  constexpr int S = 2048, E3 = 3072;
  __shared__ alignas(16) bf16 Ks[3][64 * 64];   // 24 KB
  __shared__ alignas(16) bf16 Vs[3][64 * 64];   // 24 KB (key-permuted cols)

  const int tid  = threadIdx.x;
  const int lane = tid & 63;
  const int w    = tid >> 6;       // 0..3
  const int bx = blockIdx.x;       // 0..7 -> tiles bx and 15-bx
  const int bh = blockIdx.y;
  const int b = bh >> 4, h = bh & 15;
  const int l15 = lane & 15, l16 = lane >> 4;

  // staging geometry: wave w stages 1KB chunks 2w, 2w+1 of each 64x64 tile.
  const int sr  = lane >> 3;             // 0..7 (row & 7 -> swizzle xor)
  const int scc = lane & 7;              // 16B slot
  const int r0 = w * 16 + sr;            // rows for chunk 2w
  const int r1 = w * 16 + 8 + sr;        // rows for chunk 2w+1
  const bf16* kst0 = qkv + (size_t)(b * S + r0) * E3 + 1024 + h * 64 + 8 * (scc ^ sr);
  const bf16* kst1 = qkv + (size_t)(b * S + r1) * E3 + 1024 + h * 64 + 8 * (scc ^ sr);
  const bf16* vst0 = vt + (size_t)(bh * 64 + r0) * S + 8 * (scc ^ sr);
  const bf16* vst1 = vt + (size_t)(bh * 64 + r1) * S + 8 * (scc ^ sr);

  // hoisted LDS byte offsets (row stride 128B; XOR term reduces to l15&7)
  const int xsw = l15 & 7;
  const uint32_t rdA = (uint32_t)(l15 * 128 + 16 * (l16 ^ xsw));        // chunk 0
  const uint32_t rdB = (uint32_t)(l15 * 128 + 16 * ((4 + l16) ^ xsw));  // chunk 1

#define KV_STAGE(buf, kv0_)                                          \
  {                                                                  \
    async_copy16(Ks[buf] + (w * 2) * 512,     kst0 + (size_t)(kv0_) * E3); \
    async_copy16(Ks[buf] + (w * 2 + 1) * 512, kst1 + (size_t)(kv0_) * E3); \
    async_copy16(Vs[buf] + (w * 2) * 512,     vst0 + (kv0_));        \
    async_copy16(Vs[buf] + (w * 2 + 1) * 512, vst1 + (kv0_));        \
  }

  for (int half = 0; half < 2; ++half) {
    const int t = half ? (15 - bx) : bx;
    const int q0 = t * 128;
    const int wq0 = q0 + w * 32;         // first q row owned by this wave
    const int nsteps = 2 * t + 2;        // >= 2, even

    // prologue: stage tiles 0,1 into buffers 0,1; load Q fragments
    KV_STAGE(0, 0)
    KV_STAGE(1, 64)

    bf16x8 qf[2][2];
    {
      const bf16* qbase = qkv + (size_t)(b * S + wq0) * E3 + h * 64;
#pragma unroll
      for (int s = 0; s < 2; ++s)
#pragma unroll
        for (int dk = 0; dk < 2; ++dk)
          qf[s][dk] = *(const bf16x8*)(qbase + (size_t)(s * 16 + l15) * E3 + (dk * 4 + l16) * 8);
    }

    float lstate[2] = {0.f, 0.f};
    f32x4 oacc[2][4];
    f32x4 zf = {0.f, 0.f, 0.f, 0.f};
#pragma unroll
    for (int s = 0; s < 2; ++s)
#pragma unroll
      for (int i = 0; i < 4; ++i) oacc[s][i] = zf;

    __syncthreads();   // full drain: tiles 0,1 + qf complete; invariant set

    int bufc = 0;      // kt % 3 (read)
    int bufs = 2;      // (kt+2) % 3 (stage target)
    for (int kt = 0; kt < nsteps; ++kt) {
      if (kt > 0) {
        // own tile-kt loads drained (newest 4 = tile kt+1 stay in flight)
        if (kt < nsteps - 1) { asm volatile("s_waitcnt vmcnt(4)" ::: "memory"); }
        else                 { asm volatile("s_waitcnt vmcnt(0)" ::: "memory"); }
        __builtin_amdgcn_s_barrier();
        asm volatile("" ::: "memory");
      }
      if (kt + 2 < nsteps) KV_STAGE(bufs, (kt + 2) * 64)

      const int kv0 = kt * 64;
      if (kv0 <= wq0 + 31) {   // wave-uniform dead-step skip
        const char* Kb = (const char*)Ks[bufc];
        const char* Vb = (const char*)Vs[bufc];
        f32x4 sv[2][4];
#pragma unroll
        for (int kf = 0; kf < 4; ++kf) { sv[0][kf] = zf; sv[1][kf] = zf; }
        __builtin_amdgcn_s_setprio(1);
#pragma unroll
        for (int kf = 0; kf < 4; ++kf) {
          bf16x8 k0 = *(const bf16x8*)(Kb + rdA + kf * 2048);
          sv[0][kf] = __builtin_amdgcn_mfma_f32_16x16x32_bf16(k0, qf[0][0], sv[0][kf], 0, 0, 0);
          sv[1][kf] = __builtin_amdgcn_mfma_f32_16x16x32_bf16(k0, qf[1][0], sv[1][kf], 0, 0, 0);
          bf16x8 k1 = *(const bf16x8*)(Kb + rdB + kf * 2048);
          sv[0][kf] = __builtin_amdgcn_mfma_f32_16x16x32_bf16(k1, qf[0][1], sv[0][kf], 0, 0, 0);
          sv[1][kf] = __builtin_amdgcn_mfma_f32_16x16x32_bf16(k1, qf[1][1], sv[1][kf], 0, 0, 0);
        }
        __builtin_amdgcn_s_setprio(0);

        bf16x8 pb[2][2];
#pragma unroll
        for (int s = 0; s < 2; ++s) {
          if (kv0 + 63 > wq0 + s * 16) {   // causal mask, per set
            const int qrow_ = wq0 + s * 16 + l15;
#pragma unroll
            for (int kf = 0; kf < 4; ++kf)
#pragma unroll
              for (int reg = 0; reg < 4; ++reg) {
                int key = kv0 + kf * 16 + l16 * 4 + reg;
                if (key > qrow_) sv[s][kf][reg] = -1e30f;
              }
          }
          float rsum = 0.f;
#pragma unroll
          for (int kf = 0; kf < 4; ++kf)
#pragma unroll
            for (int reg = 0; reg < 4; ++reg) {
              float p = __builtin_amdgcn_exp2f(sv[s][kf][reg]);
              sv[s][kf][reg] = p;
              rsum += p;
            }
          rsum += __shfl_xor(rsum, 16);
          rsum += __shfl_xor(rsum, 32);
          lstate[s] += rsum;
#pragma unroll
          for (int kc = 0; kc < 2; ++kc) {
            bf16x8 tq;
            tq[0] = (bf16)sv[s][2 * kc][0];  tq[1] = (bf16)sv[s][2 * kc][1];
            tq[2] = (bf16)sv[s][2 * kc][2];  tq[3] = (bf16)sv[s][2 * kc][3];
            tq[4] = (bf16)sv[s][2 * kc + 1][0]; tq[5] = (bf16)sv[s][2 * kc + 1][1];
            tq[6] = (bf16)sv[s][2 * kc + 1][2]; tq[7] = (bf16)sv[s][2 * kc + 1][3];
            pb[s][kc] = tq;
          }
        }

        __builtin_amdgcn_s_setprio(1);
#pragma unroll
        for (int nf = 0; nf < 4; ++nf) {
          bf16x8 vf0 = *(const bf16x8*)(Vb + rdA + nf * 2048);
          oacc[0][nf] = __builtin_amdgcn_mfma_f32_16x16x32_bf16(vf0, pb[0][0], oacc[0][nf], 0, 0, 0);
          oacc[1][nf] = __builtin_amdgcn_mfma_f32_16x16x32_bf16(vf0, pb[1][0], oacc[1][nf], 0, 0, 0);
          bf16x8 vf1 = *(const bf16x8*)(Vb + rdB + nf * 2048);
          oacc[0][nf] = __builtin_amdgcn_mfma_f32_16x16x32_bf16(vf1, pb[0][1], oacc[0][nf], 0, 0, 0);
          oacc[1][nf] = __builtin_amdgcn_mfma_f32_16x16x32_bf16(vf1, pb[1][1], oacc[1][nf], 0, 0, 0);
        }
        __builtin_amdgcn_s_setprio(0);
      }
      bufc = (bufc == 2) ? 0 : bufc + 1;
      bufs = (bufs == 2) ? 0 : bufs + 1;
    }

    __syncthreads();   // all waves done reading before next half restages

    // ---- normalize and store: lane owns q row per set; d = nf*16 + l16*4 + reg
#pragma unroll
    for (int s = 0; s < 2; ++s) {
      float inv = 1.0f / lstate[s];
      int qrow = wq0 + s * 16 + l15;
#pragma unroll
      for (int nf = 0; nf < 4; ++nf) {
        bf16x4 o4 = { (bf16)(oacc[s][nf][0] * inv), (bf16)(oacc[s][nf][1] * inv),
                      (bf16)(oacc[s][nf][2] * inv), (bf16)(oacc[s][nf][3] * inv) };
        *(bf16x4*)(obuf + (size_t)(b * S + qrow) * 1024 + h * 64 + nf * 16 + l16 * 4) = o4;
      }
    }
  }
#undef KV_STAGE
}

// ---------------------------------------------------------------------------
extern "C" void kernel_launch(void* const* d_in, const int* in_sizes, int n_in,
                              void* d_out, int out_size, void* d_ws, size_t ws_size,
                              hipStream_t stream) {
  (void)in_sizes; (void)n_in; (void)out_size; (void)ws_size;
  const float* x      = (const float*)d_in[0];
  const float* w_attn = (const float*)d_in[1];
  const float* b_attn = (const float*)d_in[2];
  const float* w_proj = (const float*)d_in[3];
  const float* b_proj = (const float*)d_in[4];
  float* out = (float*)d_out;

  char* ws = (char*)d_ws;
  bf16* xb  = (bf16*)(ws + 0);          // 8192*1024*2  = 16777216
  bf16* wat = (bf16*)(ws + 16777216);   // 3072*1024*2  =  6291456
  bf16* wpt = (bf16*)(ws + 23068672);   // 1024*1024*2  =  2097152
  bf16* qkv = (bf16*)(ws + 25165824);   // 8192*3072*2  = 50331648
  bf16* vt  = (bf16*)(ws + 75497472);   // 64*64*2048*2 = 16777216
  bf16* ob  = (bf16*)(ws + 92274688);   // 8192*1024*2  = 16777216 (end 109051904)

  const float QSCALE = 0.18033688011112042f;   // log2(e) / sqrt(64)

  cast_x_kernel<<<2048, 256, 0, stream>>>(x, xb, 8192 * 1024 / 4);
  transpose_cast_kernel<<<dim3(48, 16), 256, 0, stream>>>(w_attn, wat, 1024, 3072);
  transpose_cast_kernel<<<dim3(16, 16), 256, 0, stream>>>(w_proj, wpt, 1024, 1024);
  // QKV (+fused V-transpose): grid (8192/256)*(3072/128) = 768 blocks (%8==0)
  gemm256_kernel<bf16, true><<<768, 512, 0, stream>>>(xb, wat, b_attn, qkv, vt,
                                                      8192, 3072, 1024, QSCALE, 1024, 24);
  flash_kernel<<<dim3(8, 64), 256, 0, stream>>>(qkv, vt, ob);
  // proj: grid (8192/256)*(1024/128) = 256 blocks (%8==0)
  gemm256_kernel<float, false><<<256, 512, 0, stream>>>(ob, wpt, b_proj, out, nullptr,
                                                        8192, 1024, 1024, 1.0f, 0, 8);
}

// Round 15
// 154.523 us; speedup vs baseline: 1.1199x; 1.0303x over previous
//
#include <hip/hip_runtime.h>
#include <stdint.h>

// ============================================================================
// Fused attention block: out = proj( MHA_causal( x @ w_attn + b_attn ) )
// B=4, S=2048, E=1024, H=16, D=64.  bf16 MFMA path, f32 accumulation.
//
// Pipeline (best-of-each recombination):
//   1) cast_x_kernel:        x f32 -> xb bf16                  [8192][1024]
//   2) transpose_cast:       w_attn -> wat bf16 [3072][1024] (B^T form)
//                            w_proj -> wpt bf16 [1024][1024]
//   3) gemm256<bf16,FUSE_VT>: qkv(Q,K) + vt(V) = xb @ wat^T + b [8192][3072]
//        v4 schedule (BK=32, triple-buffer, counted vmcnt(3), 1 barrier/tile)
//        + fused V-transpose into vt (key-permuted; V not written to qkv).
//        Q columns (<1024) pre-scaled by log2e/8 for exp2-domain softmax.
//   4) flash_kernel v6 (round-10 measured-best, <=63.8us): causal attention
//        512 thr, 8 waves x 16 rows, paired (bx,15-bx) -> 36 steps/block,
//        K/V double-buffer + __syncthreads/step, no-max exp2 softmax,
//        in-lane P pack (vt key axis pre-permuted). v7-v11 schedule variants
//        all regressed (VGPR/occupancy/balance trade-offs); this is the floor
//        config for this structure.
//   5) gemm256<float>:       out = ob @ wpt^T + b_proj         [8192][1024]
// ============================================================================

typedef __bf16 bf16;
typedef __bf16 bf16x4 __attribute__((ext_vector_type(4)));
typedef __bf16 bf16x8 __attribute__((ext_vector_type(8)));
typedef float  f32x4  __attribute__((ext_vector_type(4)));

#define DEV __device__ __forceinline__

// async global->LDS, 16B per lane. LDS dest: wave-uniform base; HW adds lane*16.
DEV void async_copy16(bf16* lds, const bf16* g) {
  __builtin_amdgcn_global_load_lds(
      (__attribute__((address_space(1))) void*)(uintptr_t)g,
      (__attribute__((address_space(3))) void*)(uint32_t)(uintptr_t)lds,
      16, 0, 0);
}

// ---------------------------------------------------------------------------
// prep kernels
// ---------------------------------------------------------------------------
__global__ __launch_bounds__(256) void cast_x_kernel(const float* __restrict__ in,
                                                     bf16* __restrict__ out, int n4) {
  int i = blockIdx.x * blockDim.x + threadIdx.x;
  int stride = gridDim.x * blockDim.x;
  for (; i < n4; i += stride) {
    float4 v = ((const float4*)in)[i];
    bf16x4 o = { (bf16)v.x, (bf16)v.y, (bf16)v.z, (bf16)v.w };
    *(bf16x4*)(out + (size_t)i * 4) = o;
  }
}

// W [Kd][Nd] f32 row-major  ->  Wt [Nd][Kd] bf16 row-major
__global__ __launch_bounds__(256) void transpose_cast_kernel(const float* __restrict__ W,
                                                             bf16* __restrict__ Wt,
                                                             int Kd, int Nd) {
  __shared__ alignas(16) bf16 T[64 * 80];   // 64x64 tile, padded rows
  const int t = threadIdx.x;
  const int n0 = blockIdx.x * 64;
  const int k0 = blockIdx.y * 64;
#pragma unroll
  for (int i = 0; i < 4; ++i) {
    int idx = t + i * 256;            // 1024 float4s
    int r  = idx >> 4;                // k row in tile
    int c4 = (idx & 15) * 4;          // n col in tile
    float4 v = *(const float4*)(W + (size_t)(k0 + r) * Nd + n0 + c4);
    bf16x4 o = { (bf16)v.x, (bf16)v.y, (bf16)v.z, (bf16)v.w };
    *(bf16x4*)(&T[r * 80 + c4]) = o;
  }
  __syncthreads();
#pragma unroll
  for (int i = 0; i < 2; ++i) {
    int idx = t + i * 256;            // 512 out-chunks
    int n = idx >> 3;
    int c = idx & 7;
    bf16x8 o;
#pragma unroll
    for (int j = 0; j < 8; ++j) o[j] = T[(c * 8 + j) * 80 + n];
    *(bf16x8*)(Wt + (size_t)(n0 + n) * Kd + k0 + c * 8) = o;
  }
}

// ---------------------------------------------------------------------------
// GEMM v5: C[M][N] = A[M][K] @ Bt[N][K]^T + bias[N]
// BM=256, BN=128, BK=32. 512 thr = 8 waves (4M x 2N), 64x64 per wave.
// Triple-buffered LDS (72 KB, 2 blocks/CU), one barrier/K-tile, counted
// vmcnt(3), slot^=(row>>1)&3 swizzle, XCD-bijective block swizzle.
// FUSE_VT: cols in [2048,3072) are written to vtout[bh][d][perm(s)] instead
// of C (inverse of the flash in-lane-pack key permutation); others to C.
// ---------------------------------------------------------------------------
template <typename OutT, bool FUSE_VT>
__global__ __launch_bounds__(512, 4) void gemm256_kernel(const bf16* __restrict__ A,
                                                         const bf16* __restrict__ Bt,
                                                         const float* __restrict__ bias,
                                                         OutT* __restrict__ C,
                                                         bf16* __restrict__ vtout,
                                                         int M, int N, int K,
                                                         float qscale, int qcols,
                                                         int nbx) {
  __shared__ alignas(16) bf16 As[3][256 * 32];   // 48 KB
  __shared__ alignas(16) bf16 Bs[3][128 * 32];   // 24 KB

  const int tid  = threadIdx.x;
  const int lane = tid & 63;
  const int w    = tid >> 6;
  const int wm = w >> 1, wn = w & 1;
  const int l15 = lane & 15, l16 = lane >> 4;

  const int nwg = (int)gridDim.x;
  const int cpx = nwg >> 3;
  const int swz = ((int)blockIdx.x & 7) * cpx + ((int)blockIdx.x >> 3);
  const int m0 = (swz / nbx) * 256;
  const int n0 = (swz % nbx) * 128;

  const int c0  = w * 64 + lane;                 // chunk for A j=0 and B
  const int rA0 = c0 >> 2, sA0 = c0 & 3;
  const int rA1 = rA0 + 128;                     // A j=1 (c0+512)
  const bf16* srcA0 = A  + (size_t)(m0 + rA0) * K + 8 * (sA0 ^ ((rA0 >> 1) & 3));
  const bf16* srcA1 = A  + (size_t)(m0 + rA1) * K + 8 * (sA0 ^ ((rA1 >> 1) & 3));
  const bf16* srcB  = Bt + (size_t)(n0 + rA0) * K + 8 * (sA0 ^ ((rA0 >> 1) & 3));

#define STAGE_TILE(buf, kt)                                       \
  {                                                               \
    const int k0_ = (kt) * 32;                                    \
    async_copy16(&As[buf][(w * 64) * 8],         srcA0 + k0_);    \
    async_copy16(&As[buf][(512 + w * 64) * 8],   srcA1 + k0_);    \
    async_copy16(&Bs[buf][(w * 64) * 8],         srcB  + k0_);    \
  }

  f32x4 acc[4][4];
  f32x4 zf = {0.f, 0.f, 0.f, 0.f};
#pragma unroll
  for (int i = 0; i < 4; ++i)
#pragma unroll
    for (int j = 0; j < 4; ++j) acc[i][j] = zf;

  const int KT = K >> 5;
  STAGE_TILE(0, 0)
  STAGE_TILE(1, 1)

  const int soff = 8 * (l16 ^ ((l15 >> 1) & 3));

  int bufc = 0;
  int bufs = 2;
  for (int kt = 0; kt < KT; ++kt) {
    if (kt < KT - 1) { asm volatile("s_waitcnt vmcnt(3)" ::: "memory"); }
    else             { asm volatile("s_waitcnt vmcnt(0)" ::: "memory"); }
    __builtin_amdgcn_s_barrier();
    asm volatile("" ::: "memory");
    if (kt + 2 < KT) STAGE_TILE(bufs, kt + 2)

    bf16x8 bfr[4], afr[4];
#pragma unroll
    for (int n = 0; n < 4; ++n) {
      int rb = wn * 64 + n * 16 + l15;
      bfr[n] = *(const bf16x8*)(&Bs[bufc][rb * 32 + soff]);
    }
#pragma unroll
    for (int m = 0; m < 4; ++m) {
      int ra = wm * 64 + m * 16 + l15;
      afr[m] = *(const bf16x8*)(&As[bufc][ra * 32 + soff]);
    }
    __builtin_amdgcn_s_setprio(1);
#pragma unroll
    for (int m = 0; m < 4; ++m)
#pragma unroll
      for (int n = 0; n < 4; ++n)
        acc[m][n] = __builtin_amdgcn_mfma_f32_16x16x32_bf16(afr[m], bfr[n], acc[m][n], 0, 0, 0);
    __builtin_amdgcn_s_setprio(0);
    asm volatile("" ::: "memory");
    bufc = (bufc == 2) ? 0 : bufc + 1;
    bufs = (bufs == 2) ? 0 : bufs + 1;
  }

  // ---- epilogue
#pragma unroll
  for (int n = 0; n < 4; ++n) {
    int col = n0 + wn * 64 + n * 16 + l15;
    float bb = bias[col];
    if (FUSE_VT && col >= 2048) {
      // V column: write to vt[bh][d][perm(s)] (inverse of flash key permute)
      int hh = (col - 2048) >> 6, d = (col - 2048) & 63;
#pragma unroll
      for (int m = 0; m < 4; ++m) {
#pragma unroll
        for (int reg = 0; reg < 4; ++reg) {
          int row = m0 + wm * 64 + m * 16 + l16 * 4 + reg;
          int s = row & 2047;
          int key = s & 63;
          int pos = (key & 32) | (((key >> 2) & 3) << 3) | (((key >> 4) & 1) << 2) | (key & 3);
          size_t vtaddr = ((size_t)((row >> 11) * 16 + hh) * 64 + d) * 2048 + (s & ~63) + pos;
          vtout[vtaddr] = (bf16)(acc[m][n][reg] + bb);
        }
      }
    } else {
      float sc2 = (col < qcols) ? qscale : 1.0f;
#pragma unroll
      for (int m = 0; m < 4; ++m) {
#pragma unroll
        for (int reg = 0; reg < 4; ++reg) {
          int row = m0 + wm * 64 + m * 16 + l16 * 4 + reg;
          C[(size_t)row * N + col] = (OutT)((acc[m][n][reg] + bb) * sc2);
        }
      }
    }
  }
#undef STAGE_TILE
}

// ---------------------------------------------------------------------------
// Flash attention v6 (round-10 measured-best config). Q-tile 128 rows,
// 8 waves x 16 rows. Pair (bx, 15-bx) processed sequentially -> 36 KV-steps
// per block (perfect balance at 2 blocks/CU). launch_bounds(512,4): VGPR ~52.
// NO-MAX exp2 softmax (Q pre-scaled by log2e/8; masked entries exp2(-1e30)=0).
// P never touches LDS (vt key axis pre-permuted at QKV-GEMM epilogue;
// in-lane pack: pb[kc] = {sv[2kc][0..3], sv[2kc+1][0..3]}).
// S^T = mfma(K,Q): lane holds col q = lane&15, 16 keys = kf*16 + l16*4 + reg.
// O^T = mfma(V^T,P^T): lane holds col q = lane&15, d = nf*16 + l16*4 + reg.
// LDS = 32 KB (K/V double-buffer only).
// ---------------------------------------------------------------------------
__global__ __launch_bounds__(512, 4) void flash_kernel(const bf16* __restrict__ qkv,
                                                       const bf16* __restrict__ vt,
                                                       bf16* __restrict__ obuf) {
  constexpr int S = 2048, E3 = 3072;
  __shared__ alignas(16) bf16 Ks[2][64 * 64];
  __shared__ alignas(16) bf16 Vs[2][64 * 64];   // V^T tile (key-permuted cols)

  const int tid  = threadIdx.x;
  const int lane = tid & 63;
  const int w    = tid >> 6;
  const int bx = blockIdx.x;      // 0..7 -> tiles bx and 15-bx
  const int bh = blockIdx.y;
  const int b = bh >> 4, h = bh & 15;
  const int l15 = lane & 15, l16 = lane >> 4;

  // staging geometry (wave w stages 1KB chunk w of each 64x64 tile)
  const int sr  = w * 8 + (lane >> 3);   // row 0..63 within tile
  const int scc = lane & 7;              // 16B slot
  const bf16* kstage = qkv + (size_t)(b * S + sr) * E3 + 1024 + h * 64 + 8 * (scc ^ (sr & 7));
  const bf16* vstage = vt + (size_t)(bh * 64 + sr) * S + 8 * (scc ^ (sr & 7));

  // hoisted LDS byte offsets (row stride 128B; XOR term reduces to l15&7)
  const int xsw = l15 & 7;
  const uint32_t rdA = (uint32_t)(l15 * 128 + 16 * (l16 ^ xsw));        // chunk 0
  const uint32_t rdB = (uint32_t)(l15 * 128 + 16 * ((4 + l16) ^ xsw));  // chunk 1

#define KV_STAGE(buf, kv0_)                                        \
  {                                                                \
    async_copy16(Ks[buf] + w * 512, kstage + (size_t)(kv0_) * E3); \
    async_copy16(Vs[buf] + w * 512, vstage + (kv0_));              \
  }

  for (int half = 0; half < 2; ++half) {
    const int t = half ? (15 - bx) : bx;
    const int q0 = t * 128;
    const int wq0 = q0 + w * 16;         // first q row owned by this wave
    const int nsteps = 2 * t + 2;        // even

    KV_STAGE(0, 0)

    // Q fragments global->reg (B-operand: col q = l15, k-chunk dk*32+l16*8)
    bf16x8 qf[2];
    {
      const bf16* qbase = qkv + (size_t)(b * S + wq0 + l15) * E3 + h * 64;
#pragma unroll
      for (int dk = 0; dk < 2; ++dk)
        qf[dk] = *(const bf16x8*)(qbase + (dk * 4 + l16) * 8);
    }

    float lstate = 0.f;
    f32x4 oacc[4];
    f32x4 zf = {0.f, 0.f, 0.f, 0.f};
#pragma unroll
    for (int i = 0; i < 4; ++i) oacc[i] = zf;

    __syncthreads();   // step-0 K/V staged (vmcnt drained by barrier)

#define FLASH_STEP(CUR, STEPIDX)                                                  \
    {                                                                             \
      const int kv0 = (STEPIDX) * 64;                                             \
      if ((STEPIDX) + 1 < nsteps) KV_STAGE((CUR) ^ 1, kv0 + 64)                   \
      if (kv0 <= wq0 + 15) {   /* wave-uniform dead-step skip */                  \
        f32x4 sv[4];                                                              \
        _Pragma("unroll")                                                         \
        for (int kf = 0; kf < 4; ++kf) sv[kf] = zf;                               \
        __builtin_amdgcn_s_setprio(1);                                            \
        _Pragma("unroll")                                                         \
        for (int kf = 0; kf < 4; ++kf) {                                          \
          bf16x8 k0 = *(const bf16x8*)((const char*)Ks[CUR] + rdA + kf * 2048);   \
          sv[kf] = __builtin_amdgcn_mfma_f32_16x16x32_bf16(k0, qf[0], sv[kf], 0, 0, 0); \
          bf16x8 k1 = *(const bf16x8*)((const char*)Ks[CUR] + rdB + kf * 2048);   \
          sv[kf] = __builtin_amdgcn_mfma_f32_16x16x32_bf16(k1, qf[1], sv[kf], 0, 0, 0); \
        }                                                                         \
        __builtin_amdgcn_s_setprio(0);                                            \
        if (kv0 + 63 > wq0) {   /* causal mask (diagonal-crossing steps only) */  \
          const int qrow_ = wq0 + l15;                                            \
          _Pragma("unroll")                                                       \
          for (int kf = 0; kf < 4; ++kf)                                          \
            _Pragma("unroll")                                                     \
            for (int reg = 0; reg < 4; ++reg) {                                   \
              int key = kv0 + kf * 16 + l16 * 4 + reg;                            \
              if (key > qrow_) sv[kf][reg] = -1e30f;                              \
            }                                                                     \
        }                                                                         \
        float rsum = 0.f;                                                         \
        _Pragma("unroll")                                                         \
        for (int kf = 0; kf < 4; ++kf)                                            \
          _Pragma("unroll")                                                       \
          for (int reg = 0; reg < 4; ++reg) {                                     \
            float p = __builtin_amdgcn_exp2f(sv[kf][reg]);                        \
            sv[kf][reg] = p;                                                      \
            rsum += p;                                                            \
          }                                                                       \
        rsum += __shfl_xor(rsum, 16);                                             \
        rsum += __shfl_xor(rsum, 32);                                             \
        lstate += rsum;                                                           \
        /* in-lane P pack: pb[kc] covers permuted key positions kc*32+8g+j */     \
        bf16x8 pb[2];                                                             \
        _Pragma("unroll")                                                         \
        for (int kc = 0; kc < 2; ++kc) {                                          \
          bf16x8 tq;                                                              \
          tq[0] = (bf16)sv[2 * kc][0];  tq[1] = (bf16)sv[2 * kc][1];              \
          tq[2] = (bf16)sv[2 * kc][2];  tq[3] = (bf16)sv[2 * kc][3];              \
          tq[4] = (bf16)sv[2 * kc + 1][0]; tq[5] = (bf16)sv[2 * kc + 1][1];       \
          tq[6] = (bf16)sv[2 * kc + 1][2]; tq[7] = (bf16)sv[2 * kc + 1][3];       \
          pb[kc] = tq;                                                            \
        }                                                                         \
        __builtin_amdgcn_s_setprio(1);                                            \
        _Pragma("unroll")                                                         \
        for (int nf = 0; nf < 4; ++nf) {                                          \
          bf16x8 vf0 = *(const bf16x8*)((const char*)Vs[CUR] + rdA + nf * 2048);  \
          oacc[nf] = __builtin_amdgcn_mfma_f32_16x16x32_bf16(vf0, pb[0], oacc[nf], 0, 0, 0); \
          bf16x8 vf1 = *(const bf16x8*)((const char*)Vs[CUR] + rdB + nf * 2048);  \
          oacc[nf] = __builtin_amdgcn_mfma_f32_16x16x32_bf16(vf1, pb[1], oacc[nf], 0, 0, 0); \
        }                                                                         \
        __builtin_amdgcn_s_setprio(0);                                            \
      }                                                                           \
      __syncthreads();   /* next buffer staged + all waves done with CUR */       \
    }

    for (int step = 0; step < nsteps; step += 2) {
      FLASH_STEP(0, step)
      FLASH_STEP(1, step + 1)
    }
#undef FLASH_STEP

    // ---- normalize and store: lane owns q row; d = nf*16 + l16*4 + reg
    float inv = 1.0f / lstate;
    int qrow = wq0 + l15;
#pragma unroll
    for (int nf = 0; nf < 4; ++nf) {
      bf16x4 o4 = { (bf16)(oacc[nf][0] * inv), (bf16)(oacc[nf][1] * inv),
                    (bf16)(oacc[nf][2] * inv), (bf16)(oacc[nf][3] * inv) };
      *(bf16x4*)(obuf + (size_t)(b * S + qrow) * 1024 + h * 64 + nf * 16 + l16 * 4) = o4;
    }
  }
#undef KV_STAGE
}

// ---------------------------------------------------------------------------
extern "C" void kernel_launch(void* const* d_in, const int* in_sizes, int n_in,
                              void* d_out, int out_size, void* d_ws, size_t ws_size,
                              hipStream_t stream) {
  (void)in_sizes; (void)n_in; (void)out_size; (void)ws_size;
  const float* x      = (const float*)d_in[0];
  const float* w_attn = (const float*)d_in[1];
  const float* b_attn = (const float*)d_in[2];
  const float* w_proj = (const float*)d_in[3];
  const float* b_proj = (const float*)d_in[4];
  float* out = (float*)d_out;

  char* ws = (char*)d_ws;
  bf16* xb  = (bf16*)(ws + 0);          // 8192*1024*2  = 16777216
  bf16* wat = (bf16*)(ws + 16777216);   // 3072*1024*2  =  6291456
  bf16* wpt = (bf16*)(ws + 23068672);   // 1024*1024*2  =  2097152
  bf16* qkv = (bf16*)(ws + 25165824);   // 8192*3072*2  = 50331648
  bf16* vt  = (bf16*)(ws + 75497472);   // 64*64*2048*2 = 16777216
  bf16* ob  = (bf16*)(ws + 92274688);   // 8192*1024*2  = 16777216 (end 109051904)

  const float QSCALE = 0.18033688011112042f;   // log2(e) / sqrt(64)

  cast_x_kernel<<<2048, 256, 0, stream>>>(x, xb, 8192 * 1024 / 4);
  transpose_cast_kernel<<<dim3(48, 16), 256, 0, stream>>>(w_attn, wat, 1024, 3072);
  transpose_cast_kernel<<<dim3(16, 16), 256, 0, stream>>>(w_proj, wpt, 1024, 1024);
  // QKV (+fused V-transpose): grid (8192/256)*(3072/128) = 768 blocks (%8==0)
  gemm256_kernel<bf16, true><<<768, 512, 0, stream>>>(xb, wat, b_attn, qkv, vt,
                                                      8192, 3072, 1024, QSCALE, 1024, 24);
  flash_kernel<<<dim3(8, 64), 512, 0, stream>>>(qkv, vt, ob);
  // proj: grid (8192/256)*(1024/128) = 256 blocks (%8==0)
  gemm256_kernel<float, false><<<256, 512, 0, stream>>>(ob, wpt, b_proj, out, nullptr,
                                                        8192, 1024, 1024, 1.0f, 0, 8);
}

// Round 16
// 146.417 us; speedup vs baseline: 1.1819x; 1.0554x over previous
//
#include <hip/hip_runtime.h>
#include <stdint.h>

// ============================================================================
// Fused attention block: out = proj( MHA_causal( x @ w_attn + b_attn ) )
// B=4, S=2048, E=1024, H=16, D=64.  bf16 MFMA path, f32 accumulation.
//
// Pipeline:
//   1) cast_x_kernel:        x f32 -> xb bf16                  [8192][1024]
//   2) transpose_cast:       w_attn -> wat bf16 [3072][1024] (B^T form)
//                            w_proj -> wpt bf16 [1024][1024]
//   3) gemm256<bf16,FUSE_VT>: qkv(Q,K) + vt(V) = xb @ wat^T + b [8192][3072]
//        v4 schedule (BK=32, triple-buffer, counted vmcnt(3), 1 barrier/tile).
//        V-blocks (n0>=2048): COALESCED vt epilogue -- tile through LDS
//        (overlaid on staging buffers) with key-permute applied at the LDS
//        write, then 16B stores, half-wave = contiguous 512B run per (bh,d).
//        Q columns (<1024) pre-scaled by log2e/8 for exp2-domain softmax.
//   4) flash_kernel v6:      ob = causal attention             [8192][1024]
//        512 thr, 8 waves x 16 rows, paired (bx,15-bx) -> 36 steps/block,
//        K/V double-buffer, no-max exp2 softmax, in-lane P pack.
//        NEW: XCD-affinity block remap (all 8 blocks sharing a bh -> same
//        blockIdx%8 residue -> same XCD L2 caches that bh's K/V).
//   5) gemm256<float>:       out = ob @ wpt^T + b_proj         [8192][1024]
// ============================================================================

typedef __bf16 bf16;
typedef __bf16 bf16x4 __attribute__((ext_vector_type(4)));
typedef __bf16 bf16x8 __attribute__((ext_vector_type(8)));
typedef float  f32x4  __attribute__((ext_vector_type(4)));

#define DEV __device__ __forceinline__

// async global->LDS, 16B per lane. LDS dest: wave-uniform base; HW adds lane*16.
DEV void async_copy16(bf16* lds, const bf16* g) {
  __builtin_amdgcn_global_load_lds(
      (__attribute__((address_space(1))) void*)(uintptr_t)g,
      (__attribute__((address_space(3))) void*)(uint32_t)(uintptr_t)lds,
      16, 0, 0);
}

// ---------------------------------------------------------------------------
// prep kernels
// ---------------------------------------------------------------------------
__global__ __launch_bounds__(256) void cast_x_kernel(const float* __restrict__ in,
                                                     bf16* __restrict__ out, int n4) {
  int i = blockIdx.x * blockDim.x + threadIdx.x;
  int stride = gridDim.x * blockDim.x;
  for (; i < n4; i += stride) {
    float4 v = ((const float4*)in)[i];
    bf16x4 o = { (bf16)v.x, (bf16)v.y, (bf16)v.z, (bf16)v.w };
    *(bf16x4*)(out + (size_t)i * 4) = o;
  }
}

// W [Kd][Nd] f32 row-major  ->  Wt [Nd][Kd] bf16 row-major
__global__ __launch_bounds__(256) void transpose_cast_kernel(const float* __restrict__ W,
                                                             bf16* __restrict__ Wt,
                                                             int Kd, int Nd) {
  __shared__ alignas(16) bf16 T[64 * 80];   // 64x64 tile, padded rows
  const int t = threadIdx.x;
  const int n0 = blockIdx.x * 64;
  const int k0 = blockIdx.y * 64;
#pragma unroll
  for (int i = 0; i < 4; ++i) {
    int idx = t + i * 256;            // 1024 float4s
    int r  = idx >> 4;                // k row in tile
    int c4 = (idx & 15) * 4;          // n col in tile
    float4 v = *(const float4*)(W + (size_t)(k0 + r) * Nd + n0 + c4);
    bf16x4 o = { (bf16)v.x, (bf16)v.y, (bf16)v.z, (bf16)v.w };
    *(bf16x4*)(&T[r * 80 + c4]) = o;
  }
  __syncthreads();
#pragma unroll
  for (int i = 0; i < 2; ++i) {
    int idx = t + i * 256;            // 512 out-chunks
    int n = idx >> 3;
    int c = idx & 7;
    bf16x8 o;
#pragma unroll
    for (int j = 0; j < 8; ++j) o[j] = T[(c * 8 + j) * 80 + n];
    *(bf16x8*)(Wt + (size_t)(n0 + n) * Kd + k0 + c * 8) = o;
  }
}

// ---------------------------------------------------------------------------
// GEMM v6: C[M][N] = A[M][K] @ Bt[N][K]^T + bias[N]
// BM=256, BN=128, BK=32. 512 thr = 8 waves (4M x 2N), 64x64 per wave.
// Triple-buffered LDS (72 KB, 2 blocks/CU), one barrier/K-tile, counted
// vmcnt(3), slot^=(row>>1)&3 swizzle, XCD-bijective block swizzle.
// FUSE_VT + n0>=2048: coalesced vt epilogue through LDS overlay.
// ---------------------------------------------------------------------------
template <typename OutT, bool FUSE_VT>
__global__ __launch_bounds__(512, 4) void gemm256_kernel(const bf16* __restrict__ A,
                                                         const bf16* __restrict__ Bt,
                                                         const float* __restrict__ bias,
                                                         OutT* __restrict__ C,
                                                         bf16* __restrict__ vtout,
                                                         int M, int N, int K,
                                                         float qscale, int qcols,
                                                         int nbx) {
  __shared__ alignas(16) char smem[73728];               // 72 KB
  auto As = (bf16(*)[256 * 32])smem;                     // As[3][8192] (48 KB)
  auto Bs = (bf16(*)[128 * 32])(smem + 49152);           // Bs[3][4096] (24 KB)

  const int tid  = threadIdx.x;
  const int lane = tid & 63;
  const int w    = tid >> 6;
  const int wm = w >> 1, wn = w & 1;
  const int l15 = lane & 15, l16 = lane >> 4;

  const int nwg = (int)gridDim.x;
  const int cpx = nwg >> 3;
  const int swz = ((int)blockIdx.x & 7) * cpx + ((int)blockIdx.x >> 3);
  const int m0 = (swz / nbx) * 256;
  const int n0 = (swz % nbx) * 128;

  const int c0  = w * 64 + lane;                 // chunk for A j=0 and B
  const int rA0 = c0 >> 2, sA0 = c0 & 3;
  const int rA1 = rA0 + 128;                     // A j=1 (c0+512)
  const bf16* srcA0 = A  + (size_t)(m0 + rA0) * K + 8 * (sA0 ^ ((rA0 >> 1) & 3));
  const bf16* srcA1 = A  + (size_t)(m0 + rA1) * K + 8 * (sA0 ^ ((rA1 >> 1) & 3));
  const bf16* srcB  = Bt + (size_t)(n0 + rA0) * K + 8 * (sA0 ^ ((rA0 >> 1) & 3));

#define STAGE_TILE(buf, kt)                                       \
  {                                                               \
    const int k0_ = (kt) * 32;                                    \
    async_copy16(&As[buf][(w * 64) * 8],         srcA0 + k0_);    \
    async_copy16(&As[buf][(512 + w * 64) * 8],   srcA1 + k0_);    \
    async_copy16(&Bs[buf][(w * 64) * 8],         srcB  + k0_);    \
  }

  f32x4 acc[4][4];
  f32x4 zf = {0.f, 0.f, 0.f, 0.f};
#pragma unroll
  for (int i = 0; i < 4; ++i)
#pragma unroll
    for (int j = 0; j < 4; ++j) acc[i][j] = zf;

  const int KT = K >> 5;
  STAGE_TILE(0, 0)
  STAGE_TILE(1, 1)

  const int soff = 8 * (l16 ^ ((l15 >> 1) & 3));

  int bufc = 0;
  int bufs = 2;
  for (int kt = 0; kt < KT; ++kt) {
    if (kt < KT - 1) { asm volatile("s_waitcnt vmcnt(3)" ::: "memory"); }
    else             { asm volatile("s_waitcnt vmcnt(0)" ::: "memory"); }
    __builtin_amdgcn_s_barrier();
    asm volatile("" ::: "memory");
    if (kt + 2 < KT) STAGE_TILE(bufs, kt + 2)

    bf16x8 bfr[4], afr[4];
#pragma unroll
    for (int n = 0; n < 4; ++n) {
      int rb = wn * 64 + n * 16 + l15;
      bfr[n] = *(const bf16x8*)(&Bs[bufc][rb * 32 + soff]);
    }
#pragma unroll
    for (int m = 0; m < 4; ++m) {
      int ra = wm * 64 + m * 16 + l15;
      afr[m] = *(const bf16x8*)(&As[bufc][ra * 32 + soff]);
    }
    __builtin_amdgcn_s_setprio(1);
#pragma unroll
    for (int m = 0; m < 4; ++m)
#pragma unroll
      for (int n = 0; n < 4; ++n)
        acc[m][n] = __builtin_amdgcn_mfma_f32_16x16x32_bf16(afr[m], bfr[n], acc[m][n], 0, 0, 0);
    __builtin_amdgcn_s_setprio(0);
    asm volatile("" ::: "memory");
    bufc = (bufc == 2) ? 0 : bufc + 1;
    bufs = (bufs == 2) ? 0 : bufs + 1;
  }

  // ---- epilogue
  if (FUSE_VT && n0 >= 2048) {
    // V-block: coalesced vt writes via LDS overlay T[128 cols][264 rows-pad].
    // Key permute applied at LDS write (pos(key0+j) = pos(key0)|j for j<4,
    // since the permute keeps the low 2 key bits in the low 2 pos bits).
    __syncthreads();                         // all K-loop LDS reads complete
    bf16* T = (bf16*)smem;
#pragma unroll
    for (int n = 0; n < 4; ++n) {
      int c = wn * 64 + n * 16 + l15;
      float bb = bias[n0 + c];
#pragma unroll
      for (int m = 0; m < 4; ++m) {
        int r0_ = wm * 64 + m * 16 + l16 * 4;   // quad base row; key0 % 4 == 0
        int key0 = r0_ & 63;
        int pos0 = (key0 & 32) | (((key0 >> 2) & 3) << 3) | (((key0 >> 4) & 1) << 2);
        int rp = (r0_ & ~63) | pos0;
        bf16x4 q = { (bf16)(acc[m][n][0] + bb), (bf16)(acc[m][n][1] + bb),
                     (bf16)(acc[m][n][2] + bb), (bf16)(acc[m][n][3] + bb) };
        *(bf16x4*)(&T[c * 264 + rp]) = q;
      }
    }
    __syncthreads();
    const int b_  = m0 >> 11;                // batch (tiles never straddle)
    const int s0_ = m0 & 2047;
    const int ck  = tid & 31;                // 16B chunk within a 512B run
#pragma unroll
    for (int pass = 0; pass < 8; ++pass) {
      int c = pass * 16 + (tid >> 5);        // 0..127
      int colg = n0 + c - 2048;
      int hh = colg >> 6, d = colg & 63;
      bf16x8 v = *(const bf16x8*)(&T[c * 264 + ck * 8]);
      *(bf16x8*)(vtout + ((size_t)(b_ * 16 + hh) * 64 + d) * 2048 + s0_ + ck * 8) = v;
    }
    return;
  }
  // Q/K (and proj) columns: direct coalesced-ish C writes
#pragma unroll
  for (int n = 0; n < 4; ++n) {
    int col = n0 + wn * 64 + n * 16 + l15;
    float bb = bias[col];
    float sc2 = (col < qcols) ? qscale : 1.0f;
#pragma unroll
    for (int m = 0; m < 4; ++m) {
#pragma unroll
      for (int reg = 0; reg < 4; ++reg) {
        int row = m0 + wm * 64 + m * 16 + l16 * 4 + reg;
        C[(size_t)row * N + col] = (OutT)((acc[m][n][reg] + bb) * sc2);
      }
    }
  }
#undef STAGE_TILE
}

// ---------------------------------------------------------------------------
// Flash attention v6 + XCD-affinity remap. Q-tile 128 rows, 8 waves x 16.
// 1D grid 512: bh = ((i>>6)<<3)|(i&7), bx = (i>>3)&7 -- all 8 blocks sharing
// a bh have the same i%8 residue -> same XCD -> K/V L2 reuse.
// Pair (bx, 15-bx) processed sequentially -> 36 KV-steps/block.
// NO-MAX exp2 softmax (Q pre-scaled by log2e/8; masked entries exp2(-1e30)=0).
// P never touches LDS (vt key axis pre-permuted at QKV-GEMM epilogue;
// in-lane pack: pb[kc] = {sv[2kc][0..3], sv[2kc+1][0..3]}).
// S^T = mfma(K,Q): lane holds col q = lane&15, 16 keys = kf*16 + l16*4 + reg.
// O^T = mfma(V^T,P^T): lane holds col q = lane&15, d = nf*16 + l16*4 + reg.
// LDS = 32 KB (K/V double-buffer only).
// ---------------------------------------------------------------------------
__global__ __launch_bounds__(512, 4) void flash_kernel(const bf16* __restrict__ qkv,
                                                       const bf16* __restrict__ vt,
                                                       bf16* __restrict__ obuf) {
  constexpr int S = 2048, E3 = 3072;
  __shared__ alignas(16) bf16 Ks[2][64 * 64];
  __shared__ alignas(16) bf16 Vs[2][64 * 64];   // V^T tile (key-permuted cols)

  const int tid  = threadIdx.x;
  const int lane = tid & 63;
  const int w    = tid >> 6;
  const int i   = (int)blockIdx.x;          // 0..511
  const int bh  = ((i >> 6) << 3) | (i & 7);  // same-bh blocks share i%8 (XCD)
  const int bx  = (i >> 3) & 7;             // 0..7 -> tiles bx and 15-bx
  const int b = bh >> 4, h = bh & 15;
  const int l15 = lane & 15, l16 = lane >> 4;

  // staging geometry (wave w stages 1KB chunk w of each 64x64 tile)
  const int sr  = w * 8 + (lane >> 3);   // row 0..63 within tile
  const int scc = lane & 7;              // 16B slot
  const bf16* kstage = qkv + (size_t)(b * S + sr) * E3 + 1024 + h * 64 + 8 * (scc ^ (sr & 7));
  const bf16* vstage = vt + (size_t)(bh * 64 + sr) * S + 8 * (scc ^ (sr & 7));

  // hoisted LDS byte offsets (row stride 128B; XOR term reduces to l15&7)
  const int xsw = l15 & 7;
  const uint32_t rdA = (uint32_t)(l15 * 128 + 16 * (l16 ^ xsw));        // chunk 0
  const uint32_t rdB = (uint32_t)(l15 * 128 + 16 * ((4 + l16) ^ xsw));  // chunk 1

#define KV_STAGE(buf, kv0_)                                        \
  {                                                                \
    async_copy16(Ks[buf] + w * 512, kstage + (size_t)(kv0_) * E3); \
    async_copy16(Vs[buf] + w * 512, vstage + (kv0_));              \
  }

  for (int half = 0; half < 2; ++half) {
    const int t = half ? (15 - bx) : bx;
    const int q0 = t * 128;
    const int wq0 = q0 + w * 16;         // first q row owned by this wave
    const int nsteps = 2 * t + 2;        // even

    KV_STAGE(0, 0)

    // Q fragments global->reg (B-operand: col q = l15, k-chunk dk*32+l16*8)
    bf16x8 qf[2];
    {
      const bf16* qbase = qkv + (size_t)(b * S + wq0 + l15) * E3 + h * 64;
#pragma unroll
      for (int dk = 0; dk < 2; ++dk)
        qf[dk] = *(const bf16x8*)(qbase + (dk * 4 + l16) * 8);
    }

    float lstate = 0.f;
    f32x4 oacc[4];
    f32x4 zf = {0.f, 0.f, 0.f, 0.f};
#pragma unroll
    for (int i2 = 0; i2 < 4; ++i2) oacc[i2] = zf;

    __syncthreads();   // step-0 K/V staged (vmcnt drained by barrier)

#define FLASH_STEP(CUR, STEPIDX)                                                  \
    {                                                                             \
      const int kv0 = (STEPIDX) * 64;                                             \
      if ((STEPIDX) + 1 < nsteps) KV_STAGE((CUR) ^ 1, kv0 + 64)                   \
      if (kv0 <= wq0 + 15) {   /* wave-uniform dead-step skip */                  \
        f32x4 sv[4];                                                              \
        _Pragma("unroll")                                                         \
        for (int kf = 0; kf < 4; ++kf) sv[kf] = zf;                               \
        __builtin_amdgcn_s_setprio(1);                                            \
        _Pragma("unroll")                                                         \
        for (int kf = 0; kf < 4; ++kf) {                                          \
          bf16x8 k0 = *(const bf16x8*)((const char*)Ks[CUR] + rdA + kf * 2048);   \
          sv[kf] = __builtin_amdgcn_mfma_f32_16x16x32_bf16(k0, qf[0], sv[kf], 0, 0, 0); \
          bf16x8 k1 = *(const bf16x8*)((const char*)Ks[CUR] + rdB + kf * 2048);   \
          sv[kf] = __builtin_amdgcn_mfma_f32_16x16x32_bf16(k1, qf[1], sv[kf], 0, 0, 0); \
        }                                                                         \
        __builtin_amdgcn_s_setprio(0);                                            \
        if (kv0 + 63 > wq0) {   /* causal mask (diagonal-crossing steps only) */  \
          const int qrow_ = wq0 + l15;                                            \
          _Pragma("unroll")                                                       \
          for (int kf = 0; kf < 4; ++kf)                                          \
            _Pragma("unroll")                                                     \
            for (int reg = 0; reg < 4; ++reg) {                                   \
              int key = kv0 + kf * 16 + l16 * 4 + reg;                            \
              if (key > qrow_) sv[kf][reg] = -1e30f;                              \
            }                                                                     \
        }                                                                         \
        float rsum = 0.f;                                                         \
        _Pragma("unroll")                                                         \
        for (int kf = 0; kf < 4; ++kf)                                            \
          _Pragma("unroll")                                                       \
          for (int reg = 0; reg < 4; ++reg) {                                     \
            float p = __builtin_amdgcn_exp2f(sv[kf][reg]);                        \
            sv[kf][reg] = p;                                                      \
            rsum += p;                                                            \
          }                                                                       \
        rsum += __shfl_xor(rsum, 16);                                             \
        rsum += __shfl_xor(rsum, 32);                                             \
        lstate += rsum;                                                           \
        /* in-lane P pack: pb[kc] covers permuted key positions kc*32+8g+j */     \
        bf16x8 pb[2];                                                             \
        _Pragma("unroll")                                                         \
        for (int kc = 0; kc < 2; ++kc) {                                          \
          bf16x8 tq;                                                              \
          tq[0] = (bf16)sv[2 * kc][0];  tq[1] = (bf16)sv[2 * kc][1];              \
          tq[2] = (bf16)sv[2 * kc][2];  tq[3] = (bf16)sv[2 * kc][3];              \
          tq[4] = (bf16)sv[2 * kc + 1][0]; tq[5] = (bf16)sv[2 * kc + 1][1];       \
          tq[6] = (bf16)sv[2 * kc + 1][2]; tq[7] = (bf16)sv[2 * kc + 1][3];       \
          pb[kc] = tq;                                                            \
        }                                                                         \
        __builtin_amdgcn_s_setprio(1);                                            \
        _Pragma("unroll")                                                         \
        for (int nf = 0; nf < 4; ++nf) {                                          \
          bf16x8 vf0 = *(const bf16x8*)((const char*)Vs[CUR] + rdA + nf * 2048);  \
          oacc[nf] = __builtin_amdgcn_mfma_f32_16x16x32_bf16(vf0, pb[0], oacc[nf], 0, 0, 0); \
          bf16x8 vf1 = *(const bf16x8*)((const char*)Vs[CUR] + rdB + nf * 2048);  \
          oacc[nf] = __builtin_amdgcn_mfma_f32_16x16x32_bf16(vf1, pb[1], oacc[nf], 0, 0, 0); \
        }                                                                         \
        __builtin_amdgcn_s_setprio(0);                                            \
      }                                                                           \
      __syncthreads();   /* next buffer staged + all waves done with CUR */       \
    }

    for (int step = 0; step < nsteps; step += 2) {
      FLASH_STEP(0, step)
      FLASH_STEP(1, step + 1)
    }
#undef FLASH_STEP

    // ---- normalize and store: lane owns q row; d = nf*16 + l16*4 + reg
    float inv = 1.0f / lstate;
    int qrow = wq0 + l15;
#pragma unroll
    for (int nf = 0; nf < 4; ++nf) {
      bf16x4 o4 = { (bf16)(oacc[nf][0] * inv), (bf16)(oacc[nf][1] * inv),
                    (bf16)(oacc[nf][2] * inv), (bf16)(oacc[nf][3] * inv) };
      *(bf16x4*)(obuf + (size_t)(b * S + qrow) * 1024 + h * 64 + nf * 16 + l16 * 4) = o4;
    }
  }
#undef KV_STAGE
}

// ---------------------------------------------------------------------------
extern "C" void kernel_launch(void* const* d_in, const int* in_sizes, int n_in,
                              void* d_out, int out_size, void* d_ws, size_t ws_size,
                              hipStream_t stream) {
  (void)in_sizes; (void)n_in; (void)out_size; (void)ws_size;
  const float* x      = (const float*)d_in[0];
  const float* w_attn = (const float*)d_in[1];
  const float* b_attn = (const float*)d_in[2];
  const float* w_proj = (const float*)d_in[3];
  const float* b_proj = (const float*)d_in[4];
  float* out = (float*)d_out;

  char* ws = (char*)d_ws;
  bf16* xb  = (bf16*)(ws + 0);          // 8192*1024*2  = 16777216
  bf16* wat = (bf16*)(ws + 16777216);   // 3072*1024*2  =  6291456
  bf16* wpt = (bf16*)(ws + 23068672);   // 1024*1024*2  =  2097152
  bf16* qkv = (bf16*)(ws + 25165824);   // 8192*3072*2  = 50331648
  bf16* vt  = (bf16*)(ws + 75497472);   // 64*64*2048*2 = 16777216
  bf16* ob  = (bf16*)(ws + 92274688);   // 8192*1024*2  = 16777216 (end 109051904)

  const float QSCALE = 0.18033688011112042f;   // log2(e) / sqrt(64)

  cast_x_kernel<<<2048, 256, 0, stream>>>(x, xb, 8192 * 1024 / 4);
  transpose_cast_kernel<<<dim3(48, 16), 256, 0, stream>>>(w_attn, wat, 1024, 3072);
  transpose_cast_kernel<<<dim3(16, 16), 256, 0, stream>>>(w_proj, wpt, 1024, 1024);
  // QKV (+fused V-transpose): grid (8192/256)*(3072/128) = 768 blocks (%8==0)
  gemm256_kernel<bf16, true><<<768, 512, 0, stream>>>(xb, wat, b_attn, qkv, vt,
                                                      8192, 3072, 1024, QSCALE, 1024, 24);
  flash_kernel<<<512, 512, 0, stream>>>(qkv, vt, ob);
  // proj: grid (8192/256)*(1024/128) = 256 blocks (%8==0)
  gemm256_kernel<float, false><<<256, 512, 0, stream>>>(ob, wpt, b_proj, out, nullptr,
                                                        8192, 1024, 1024, 1.0f, 0, 8);
}